// Round 3
// baseline (331.825 us; speedup 1.0000x reference)
//
#include <hip/hip_runtime.h>
#include <math.h>

#define B_   8
#define C_   32
#define H_   512
#define W_   512
#define CQ_  8
#define NW_  4096          // windows per batch
#define ED_  2048
#define EH_  1024
#define EPS_ 1e-6f

#define TW 64
#define TH 16
#define XLH 18             // TH + 2 halo rows
#define XLW 68             // TW + 2 halo cols + pad (rows 16B-aligned)

__device__ __forceinline__ float leaky(float x) { return x > 0.f ? x : 0.1f * x; }
__device__ __forceinline__ float sigmoidf_(float x) { return 1.f / (1.f + __expf(-x)); }

// ---------------------------------------------------------------------------
// Pass A (fused): both 1x1 convs, LN+leaky, SA 3x3 conv, window variance,
// pooled partial sums.  grid (8, 32, 8), block 256, 4 px/thread (float4),
// double-buffered channel prefetch (4 channels deep).
// ---------------------------------------------------------------------------
__global__ __launch_bounds__(256, 3) void pass_a(
    const float* __restrict__ x,
    const float* __restrict__ w_in, const float* __restrict__ b_in,
    const float* __restrict__ w_conv, const float* __restrict__ b_conv,
    const float* __restrict__ ln_w, const float* __restrict__ ln_b,
    const float* __restrict__ w_sa, const float* __restrict__ b_sa,
    float* __restrict__ sa_out, double* __restrict__ var_out,
    float* __restrict__ pooled_part)
{
    __shared__ float xl[CQ_][XLH][XLW];      // x_ tile + halo (~38 KB)
    __shared__ float xm_lds[TH][TW];         // in_conv channel-mean (4 KB)
    __shared__ float red[4][CQ_];

    const int tid = threadIdx.x;
    const int b  = blockIdx.z;
    const int ty = blockIdx.y * TH, tx = blockIdx.x * TW;
    const int px = (tid & 15) * 4, py = tid >> 4;
    const size_t plane = (size_t)H_ * W_;
    const float* xb = x + (size_t)b * C_ * plane;
    const float* p  = xb + (size_t)(ty + py) * W_ + (tx + px);

    // halo ring mapping (164 positions; others masked)
    int hy = 0, hx = 1;
    if (tid < 66)        { hy = 0;         hx = tid + 1; }
    else if (tid < 132)  { hy = 17;        hx = tid - 65; }
    else if (tid < 148)  { hy = tid - 131; hx = 1; }
    else if (tid < 164)  { hy = tid - 147; hx = 66; }
    const int gy = ty + hy - 1, gx = tx + hx - 2;
    const bool inb = (tid < 164) && (gy >= 0) && (gy < H_) && (gx >= 0) && (gx < W_);
    const float* ph = inb ? (xb + (size_t)gy * W_ + gx) : xb;

    float ycv[CQ_][4], yin[CQ_][4], hacc[CQ_];
#pragma unroll
    for (int q = 0; q < CQ_; ++q) {
        hacc[q] = 0.f;
#pragma unroll
        for (int j = 0; j < 4; ++j) { ycv[q][j] = 0.f; yin[q][j] = 0.f; }
    }

    // ---- main loop: 8 chunks of 4 channels, double-buffered ----
    float4 ib[2][4];
    float  hb[2][4];
#pragma unroll
    for (int k = 0; k < 4; ++k) {
        ib[0][k] = *reinterpret_cast<const float4*>(p + (size_t)k * plane);
        hb[0][k] = ph[(size_t)k * plane];
    }

#pragma unroll
    for (int cb = 0; cb < 8; ++cb) {
        const int cur = cb & 1;
        if (cb < 7) {
#pragma unroll
            for (int k = 0; k < 4; ++k) {
                const int c = (cb + 1) * 4 + k;
                ib[cur ^ 1][k] = *reinterpret_cast<const float4*>(p + (size_t)c * plane);
                hb[cur ^ 1][k] = ph[(size_t)c * plane];
            }
        }
#pragma unroll
        for (int k = 0; k < 4; ++k) {
            const int c = cb * 4 + k;
            const float4 v = ib[cur][k];
            const float hv = hb[cur][k];
#pragma unroll
            for (int q = 0; q < CQ_; ++q) {
                const float wc = w_conv[q * C_ + c];   // uniform -> s_load
                const float wi = w_in[q * C_ + c];     // uniform -> s_load
                ycv[q][0] = fmaf(wc, v.x, ycv[q][0]);
                ycv[q][1] = fmaf(wc, v.y, ycv[q][1]);
                ycv[q][2] = fmaf(wc, v.z, ycv[q][2]);
                ycv[q][3] = fmaf(wc, v.w, ycv[q][3]);
                yin[q][0] = fmaf(wi, v.x, yin[q][0]);
                yin[q][1] = fmaf(wi, v.y, yin[q][1]);
                yin[q][2] = fmaf(wi, v.z, yin[q][2]);
                yin[q][3] = fmaf(wi, v.w, yin[q][3]);
                hacc[q]   = fmaf(wc, hv, hacc[q]);
            }
        }
    }

    // ---- interior post: bias, LN, leaky, xm ----
#pragma unroll
    for (int q = 0; q < CQ_; ++q) {
        const float bc = b_conv[q];
#pragma unroll
        for (int j = 0; j < 4; ++j) ycv[q][j] += bc;
    }

    float ps[CQ_];
#pragma unroll
    for (int q = 0; q < CQ_; ++q) ps[q] = 0.f;

    float xmv[4];
#pragma unroll
    for (int j = 0; j < 4; ++j) {
        float u = 0.f;
#pragma unroll
        for (int q = 0; q < CQ_; ++q) u += ycv[q][j];
        u *= 0.125f;
        float s = 0.f;
#pragma unroll
        for (int q = 0; q < CQ_; ++q) { const float d = ycv[q][j] - u; s = fmaf(d, d, s); }
        s *= 0.125f;
        const float inv = 1.f / sqrtf(s + EPS_);
        float m = 0.f;
#pragma unroll
        for (int q = 0; q < CQ_; ++q) {
            const float xv = leaky(fmaf(ln_w[q], (ycv[q][j] - u) * inv, ln_b[q]));
            ycv[q][j] = xv;          // now holds x_
            ps[q] += xv;
            m += leaky(yin[q][j] + b_in[q]);
        }
        xmv[j] = m * 0.125f;
    }

    *reinterpret_cast<float4*>(&xm_lds[py][px]) = make_float4(xmv[0], xmv[1], xmv[2], xmv[3]);
#pragma unroll
    for (int q = 0; q < CQ_; ++q) {
        *reinterpret_cast<float2*>(&xl[q][py + 1][px + 2]) = make_float2(ycv[q][0], ycv[q][1]);
        *reinterpret_cast<float2*>(&xl[q][py + 1][px + 4]) = make_float2(ycv[q][2], ycv[q][3]);
    }

    const int lane = tid & 63, wave = tid >> 6;
    // pooled partial: wave-reduce 8 channel sums
#pragma unroll
    for (int q = 0; q < CQ_; ++q) {
        float s = ps[q];
#pragma unroll
        for (int off = 32; off; off >>= 1) s += __shfl_xor(s, off);
        if (lane == 0) red[wave][q] = s;
    }

    // ---- halo post: LN on accumulated halo conv ----
    if (tid < 164) {
        float yc[CQ_];
        float u = 0.f;
#pragma unroll
        for (int q = 0; q < CQ_; ++q) { yc[q] = hacc[q] + b_conv[q]; u += yc[q]; }
        u *= 0.125f;
        float s = 0.f;
#pragma unroll
        for (int q = 0; q < CQ_; ++q) { const float d = yc[q] - u; s = fmaf(d, d, s); }
        s *= 0.125f;
        const float inv = 1.f / sqrtf(s + EPS_);
#pragma unroll
        for (int q = 0; q < CQ_; ++q) {
            const float v = leaky(fmaf(ln_w[q], (yc[q] - u) * inv, ln_b[q]));
            xl[q][hy][hx] = inb ? v : 0.f;
        }
    }

    __syncthreads();

    // ---- pooled partial store ----
    if (tid < CQ_) {
        const float s = red[0][tid] + red[1][tid] + red[2][tid] + red[3][tid];
        const int bid = (blockIdx.z * gridDim.y + blockIdx.y) * gridDim.x + blockIdx.x;
        pooled_part[bid * CQ_ + tid] = s;
    }

    // ---- spatial attention 3x3 conv + sigmoid ----
    {
        const float bsa = b_sa[0];
        float acc[4] = {bsa, bsa, bsa, bsa};
#pragma unroll
        for (int q = 0; q < CQ_; ++q) {
#pragma unroll
            for (int dy = 0; dy < 3; ++dy) {
                const float* r = &xl[q][py + dy][px];
                const float4 aa = *reinterpret_cast<const float4*>(r);
                const float4 bb = *reinterpret_cast<const float4*>(r + 4);
                const float v[8] = {aa.x, aa.y, aa.z, aa.w, bb.x, bb.y, bb.z, bb.w};
#pragma unroll
                for (int dx = 0; dx < 3; ++dx) {
                    const float w = w_sa[q * 9 + dy * 3 + dx];
#pragma unroll
                    for (int j = 0; j < 4; ++j) acc[j] = fmaf(w, v[j + dx + 1], acc[j]);
                }
            }
        }
        const float4 o = make_float4(sigmoidf_(acc[0]), sigmoidf_(acc[1]),
                                     sigmoidf_(acc[2]), sigmoidf_(acc[3]));
        *reinterpret_cast<float4*>(&sa_out[((size_t)b * H_ + (ty + py)) * W_ + tx + px]) = o;
    }

    // ---- window variance (ddof=1, double), 16 windows/block, 4 per wave ----
#pragma unroll
    for (int k = 0; k < 4; ++k) {
        const int wi = wave * 4 + k;
        const int wy = wi >> 3, wx = wi & 7;
        const double dv = (double)xm_lds[wy * 8 + (lane >> 3)][wx * 8 + (lane & 7)];
        double s = dv;
#pragma unroll
        for (int off = 32; off; off >>= 1) s += __shfl_xor(s, off);
        const double mean = s * (1.0 / 64.0);
        const double d = dv - mean;
        double s2 = d * d;
#pragma unroll
        for (int off = 32; off; off >>= 1) s2 += __shfl_xor(s2, off);
        if (lane == 0) {
            const int n = (blockIdx.y * 2 + wy) * 64 + blockIdx.x * 8 + wx;
            var_out[(size_t)b * NW_ + n] = s2 * (1.0 / 63.0);
        }
    }
}

// ---------------------------------------------------------------------------
// K2 (fused tail, independent roles):
//   blocks   0..127 : exact bottom-k rank -> maskF
//   blocks 128..383 : h1/h0 (MLP layer 1 on degenerate input)
//   block      384  : pooled reduction -> CA conv -> sigmoid
// ---------------------------------------------------------------------------
__global__ __launch_bounds__(256) void k2_kernel(
    const double* __restrict__ var, float* __restrict__ maskF,
    const float* __restrict__ w_m1, const float* __restrict__ b_m1,
    float* __restrict__ h1, float* __restrict__ h0,
    const float* __restrict__ pooled_part,
    const float* __restrict__ w_ca, const float* __restrict__ b_ca,
    float* __restrict__ ca_out)
{
    __shared__ double sv[NW_];   // 32 KB (rank); reused as float scratch by CA
    const int bi = blockIdx.x;
    const int tid = threadIdx.x;

    if (bi < 128) {
        // ---- rank: top_k-stable tie-break, exact ----
        const int b = bi >> 4;
        const double* vb = var + (size_t)b * NW_;
        for (int j = tid; j < NW_; j += 256) sv[j] = vb[j];
        __syncthreads();
        const int i = (bi & 15) * 256 + tid;
        const double vi = sv[i];
        int cnt = 0;
#pragma unroll 4
        for (int j = 0; j < NW_; ++j) {
            const double vj = sv[j];
            cnt += (vj < vi) || (vj == vi && j < i);
        }
        maskF[(size_t)b * NW_ + i] = (cnt < NW_ / 2) ? 0.f : 1.f;
    } else if (bi < 384) {
        // ---- h: h1[e] = leaky(rowsum(w_m1[e,:]) + b_m1[e]); h0 = leaky(b) ----
        const int wave = tid >> 6, lane = tid & 63;
        const int e = (bi - 128) * 4 + wave;
        const float* row = w_m1 + (size_t)e * ED_;
        float s = 0.f;
#pragma unroll
        for (int k = 0; k < ED_ / 64; ++k) s += row[lane + 64 * k];
#pragma unroll
        for (int off = 32; off; off >>= 1) s += __shfl_xor(s, off);
        if (lane == 0) {
            h1[e] = leaky(s + b_m1[e]);
            h0[e] = leaky(b_m1[e]);
        }
    } else {
        // ---- CA ----
        float* sp = (float*)sv;
        const int bq = tid >> 2, part = tid & 3;     // 64 (b,q) x 4 partials
        const int bb = bq >> 3, q = bq & 7;
        float s = 0.f;
        for (int k = part; k < 256; k += 4) s += pooled_part[((size_t)bb * 256 + k) * CQ_ + q];
        sp[tid] = s;
        __syncthreads();
        if (tid < 64)
            sp[256 + tid] = (sp[4 * tid] + sp[4 * tid + 1] + sp[4 * tid + 2] + sp[4 * tid + 3])
                            * (1.f / ((float)H_ * (float)W_));
        __syncthreads();
        const int ob = tid >> 5, o = tid & 31;
        float acc = b_ca[o];
#pragma unroll
        for (int qq = 0; qq < CQ_; ++qq)
            acc = fmaf(w_ca[o * CQ_ + qq], sp[256 + ob * CQ_ + qq], acc);
        ca_out[tid] = sigmoidf_(acc);
    }
}

// ---------------------------------------------------------------------------
// o1[f] = w_m2[f,:].h1 + b_m2[f];  o0[f] = w_m2[f,:].h0 + b_m2[f]
// ---------------------------------------------------------------------------
__global__ __launch_bounds__(256) void o_kernel(const float* __restrict__ w_m2,
                                                const float* __restrict__ b_m2,
                                                const float* __restrict__ h1,
                                                const float* __restrict__ h0,
                                                float* __restrict__ o1, float* __restrict__ o0)
{
    const int wave = threadIdx.x >> 6, lane = threadIdx.x & 63;
    const int f = blockIdx.x * 4 + wave;
    const float* row = w_m2 + (size_t)f * EH_;
    float s1 = 0.f, s0 = 0.f;
#pragma unroll
    for (int k = 0; k < EH_ / 64; ++k) {
        const float w = row[lane + 64 * k];
        s1 = fmaf(w, h1[lane + 64 * k], s1);
        s0 = fmaf(w, h0[lane + 64 * k], s0);
    }
#pragma unroll
    for (int off = 32; off; off >>= 1) {
        s1 += __shfl_xor(s1, off);
        s0 += __shfl_xor(s0, off);
    }
    if (lane == 0) {
        o1[f] = s1 + b_m2[f];
        o0[f] = s0 + b_m2[f];
    }
}

// ---------------------------------------------------------------------------
// out_mask row = mask ? o1 : o0.  grid 2048, 16 rows/block, rows in regs.
// ---------------------------------------------------------------------------
__global__ __launch_bounds__(256) void bcast_kernel(const float* __restrict__ maskF,
                                                    const float* __restrict__ o1,
                                                    const float* __restrict__ o0,
                                                    float* __restrict__ out)
{
    __shared__ float sm[16];
    const int t = threadIdx.x;
    const long row0 = (long)blockIdx.x * 16;
    if (t < 16) sm[t] = maskF[row0 + t];
    const float4 a1 = ((const float4*)o1)[t], b1 = ((const float4*)o1)[t + 256];
    const float4 a0 = ((const float4*)o0)[t], b0 = ((const float4*)o0)[t + 256];
    __syncthreads();
#pragma unroll
    for (int r = 0; r < 16; ++r) {
        float4* dst = (float4*)(out + (size_t)(row0 + r) * ED_);
        const bool m = sm[r] > 0.5f;
        dst[t]       = m ? a1 : a0;
        dst[t + 256] = m ? b1 : b0;
    }
}

extern "C" void kernel_launch(void* const* d_in, const int* in_sizes, int n_in,
                              void* d_out, int out_size, void* d_ws, size_t ws_size,
                              hipStream_t stream)
{
    const float* x    = (const float*)d_in[0];
    const float* w_in = (const float*)d_in[1];
    const float* b_in = (const float*)d_in[2];
    const float* w_cv = (const float*)d_in[3];
    const float* b_cv = (const float*)d_in[4];
    const float* lnw  = (const float*)d_in[5];
    const float* lnb  = (const float*)d_in[6];
    const float* w_ca = (const float*)d_in[7];
    const float* b_ca = (const float*)d_in[8];
    const float* w_sa = (const float*)d_in[9];
    const float* b_sa = (const float*)d_in[10];
    const float* w_m1 = (const float*)d_in[11];
    const float* b_m1 = (const float*)d_in[12];
    const float* w_m2 = (const float*)d_in[13];
    const float* b_m2 = (const float*)d_in[14];

    float* out_mask = (float*)d_out;                           // [B, NW, ED]
    float* ca_out   = out_mask + (size_t)B_ * NW_ * ED_;       // [B, C]
    float* sa_out   = ca_out + (size_t)B_ * C_;                // [B, H, W]

    char* ws = (char*)d_ws;
    double* var       = (double*)ws;                           // 256 KB
    float*  maskF     = (float*)(ws + (size_t)B_ * NW_ * 8);   // 128 KB
    float*  pooled_pp = maskF + (size_t)B_ * NW_;              // 2048*8 floats
    float*  h1 = pooled_pp + 2048 * CQ_;
    float*  h0 = h1 + EH_;
    float*  o1 = h0 + EH_;
    float*  o0 = o1 + ED_;

    pass_a<<<dim3(W_ / TW, H_ / TH, B_), 256, 0, stream>>>(
        x, w_in, b_in, w_cv, b_cv, lnw, lnb, w_sa, b_sa, sa_out, var, pooled_pp);
    k2_kernel<<<385, 256, 0, stream>>>(var, maskF, w_m1, b_m1, h1, h0,
                                       pooled_pp, w_ca, b_ca, ca_out);
    o_kernel<<<ED_ / 4, 256, 0, stream>>>(w_m2, b_m2, h1, h0, o1, o0);
    bcast_kernel<<<B_ * NW_ / 16, 256, 0, stream>>>(maskF, o1, o0, out_mask);
}